// Round 1
// baseline (692.170 us; speedup 1.0000x reference)
//
#include <hip/hip_runtime.h>
#include <math.h>

#define N_TOK 2048
#define DM    512
#define NH    8
#define DH    64
#define HID   32

// ---------------- K0: U[n][j] = xyz[n] . W1[j]  (2048 x 32) ----------------
__global__ __launch_bounds__(256) void u_kernel(const float* __restrict__ xyz,
                                                const float* __restrict__ W1,
                                                float* __restrict__ U) {
    int idx = blockIdx.x * 256 + threadIdx.x;   // 65536 total
    int n = idx >> 5, j = idx & 31;
    const float* xp = xyz + n * 3;
    const float* wp = W1 + j * 3;
    U[idx] = xp[0] * wp[0] + xp[1] * wp[1] + xp[2] * wp[2];
}

// ---------------- generic C = A[2048x512] * B[512x512]^T + bias ----------------
// BM=64, BN=64, BK=32, 256 threads (16x16), 4x4 micro-tile.
__global__ __launch_bounds__(256) void gemm_awt(const float* __restrict__ A,
                                                const float* __restrict__ Bw,
                                                const float* __restrict__ bias,
                                                float* __restrict__ C) {
    __shared__ float As[32][68];   // [k][row], pad 68 keeps ds_read_b128 16B-aligned
    __shared__ float Bs[32][68];   // [k][col]
    const int n0 = blockIdx.x * 64;
    const int m0 = blockIdx.y * 64;
    const int t  = threadIdx.x;
    const int tx = t & 15, ty = t >> 4;

    float acc[4][4] = {};

    for (int k0 = 0; k0 < 512; k0 += 32) {
        // stage A tile: 64 rows x 32 k  (512 float4, 2 per thread, coalesced)
        #pragma unroll
        for (int i = 0; i < 2; ++i) {
            int fi  = i * 256 + t;
            int row = fi >> 3, k4 = fi & 7;
            float4 a = *(const float4*)(A + (size_t)(m0 + row) * 512 + k0 + k4 * 4);
            As[k4 * 4 + 0][row] = a.x; As[k4 * 4 + 1][row] = a.y;
            As[k4 * 4 + 2][row] = a.z; As[k4 * 4 + 3][row] = a.w;
            float4 b = *(const float4*)(Bw + (size_t)(n0 + row) * 512 + k0 + k4 * 4);
            Bs[k4 * 4 + 0][row] = b.x; Bs[k4 * 4 + 1][row] = b.y;
            Bs[k4 * 4 + 2][row] = b.z; Bs[k4 * 4 + 3][row] = b.w;
        }
        __syncthreads();
        #pragma unroll
        for (int k = 0; k < 32; ++k) {
            float4 a4 = *(const float4*)&As[k][ty * 4];
            float4 b4 = *(const float4*)&Bs[k][tx * 4];
            float av[4] = {a4.x, a4.y, a4.z, a4.w};
            float bv[4] = {b4.x, b4.y, b4.z, b4.w};
            #pragma unroll
            for (int i = 0; i < 4; ++i)
                #pragma unroll
                for (int j = 0; j < 4; ++j)
                    acc[i][j] = fmaf(av[i], bv[j], acc[i][j]);
        }
        __syncthreads();
    }

    float4 b4 = *(const float4*)(bias + n0 + tx * 4);
    float bb[4] = {b4.x, b4.y, b4.z, b4.w};
    #pragma unroll
    for (int i = 0; i < 4; ++i) {
        float4 o;
        o.x = acc[i][0] + bb[0]; o.y = acc[i][1] + bb[1];
        o.z = acc[i][2] + bb[2]; o.w = acc[i][3] + bb[3];
        *(float4*)(C + (size_t)(m0 + ty * 4 + i) * 512 + n0 + tx * 4) = o;
    }
}

// ---------------- K2: fused scores + bias-MLP + softmax + attn write ----------------
// One WG per (head, 8-row block). 256 threads. Dynamic LDS ~68.6 KB -> 2 WG/CU.
__global__ __launch_bounds__(256) void attn_kernel(const float* __restrict__ q_ws,
                                                   const float* __restrict__ k_ws,
                                                   const float* __restrict__ U,
                                                   const float* __restrict__ b1,
                                                   const float* __restrict__ W2,
                                                   const float* __restrict__ b2,
                                                   float* __restrict__ attn_out) {
    extern __shared__ float sm[];
    float* s_scores = sm;                    // [8][2048]
    float* s_q      = sm + 8 * 2048;         // [8][64]
    float* s_ub     = s_q + 512;             // [8][32]  (= U[n] + b1)
    float* s_red    = s_ub + 256;            // [8]

    const int t  = threadIdx.x;
    const int h  = blockIdx.y;
    const int n0 = blockIdx.x * 8;

    for (int idx = t; idx < 512; idx += 256) {
        int r = idx >> 6, d = idx & 63;
        s_q[idx] = q_ws[(size_t)(n0 + r) * 512 + h * 64 + d];
    }
    {
        int r = t >> 5, j = t & 31;
        s_ub[t] = U[(n0 + r) * 32 + j] + b1[j];
    }
    float w2r[32];
    #pragma unroll
    for (int j4 = 0; j4 < 8; ++j4) {
        float4 w = *(const float4*)(W2 + h * 32 + j4 * 4);
        w2r[j4 * 4 + 0] = w.x; w2r[j4 * 4 + 1] = w.y;
        w2r[j4 * 4 + 2] = w.z; w2r[j4 * 4 + 3] = w.w;
    }
    const float b2h = b2[h];
    __syncthreads();

    // ---- phase 1: one column per thread per tile; all 8 rows ----
    for (int tile = 0; tile < 8; ++tile) {
        const int m = tile * 256 + t;
        float um[32];
        #pragma unroll
        for (int j4 = 0; j4 < 8; ++j4) {
            float4 u4 = *(const float4*)(U + m * 32 + j4 * 4);
            um[j4 * 4 + 0] = u4.x; um[j4 * 4 + 1] = u4.y;
            um[j4 * 4 + 2] = u4.z; um[j4 * 4 + 3] = u4.w;
        }
        float kk[64];
        #pragma unroll
        for (int d4 = 0; d4 < 16; ++d4) {
            float4 k4 = *(const float4*)(k_ws + (size_t)m * 512 + h * 64 + d4 * 4);
            kk[d4 * 4 + 0] = k4.x; kk[d4 * 4 + 1] = k4.y;
            kk[d4 * 4 + 2] = k4.z; kk[d4 * 4 + 3] = k4.w;
        }
        #pragma unroll
        for (int r = 0; r < 8; ++r) {
            const float* ubp = s_ub + r * 32;
            float bia = 0.f;
            #pragma unroll
            for (int j = 0; j < 32; j += 4) {
                float4 u4 = *(const float4*)(ubp + j);
                float t0 = fmaxf(u4.x - um[j + 0], 0.f);
                float t1 = fmaxf(u4.y - um[j + 1], 0.f);
                float t2 = fmaxf(u4.z - um[j + 2], 0.f);
                float t3 = fmaxf(u4.w - um[j + 3], 0.f);
                bia = fmaf(w2r[j + 0], t0, bia);
                bia = fmaf(w2r[j + 1], t1, bia);
                bia = fmaf(w2r[j + 2], t2, bia);
                bia = fmaf(w2r[j + 3], t3, bia);
            }
            const float* qp = s_q + r * 64;
            float qk = 0.f;
            #pragma unroll
            for (int d = 0; d < 64; d += 4) {
                float4 q4 = *(const float4*)(qp + d);
                qk = fmaf(q4.x, kk[d + 0], qk);
                qk = fmaf(q4.y, kk[d + 1], qk);
                qk = fmaf(q4.z, kk[d + 2], qk);
                qk = fmaf(q4.w, kk[d + 3], qk);
            }
            s_scores[r * 2048 + m] = qk * 0.125f + bia + b2h;
        }
    }
    __syncthreads();

    // ---- phase 2: per-row max, exp, sum (32 threads/row, stride-32 = conflict-free) ----
    {
        const int r = t >> 5, l32 = t & 31;
        float* row = s_scores + r * 2048;
        float mx = -1e30f;
        for (int c = l32; c < 2048; c += 32) mx = fmaxf(mx, row[c]);
        #pragma unroll
        for (int off = 16; off; off >>= 1) mx = fmaxf(mx, __shfl_xor(mx, off, 32));
        float l = 0.f;
        for (int c = l32; c < 2048; c += 32) {
            float e = __expf(row[c] - mx);
            row[c] = e;
            l += e;
        }
        #pragma unroll
        for (int off = 16; off; off >>= 1) l += __shfl_xor(l, off, 32);
        if (l32 == 0) s_red[r] = 1.0f / l;
    }
    __syncthreads();

    // ---- write normalized attn, coalesced float4 ----
    #pragma unroll
    for (int r = 0; r < 8; ++r) {
        const float inv = s_red[r];
        const float4* src = (const float4*)(s_scores + r * 2048);
        float4* dst = (float4*)(attn_out + ((size_t)h * N_TOK + (n0 + r)) * N_TOK);
        #pragma unroll
        for (int c = 0; c < 2; ++c) {
            int c4 = c * 256 + t;
            float4 v = src[c4];
            v.x *= inv; v.y *= inv; v.z *= inv; v.w *= inv;
            dst[c4] = v;
        }
    }
}

// ---------------- K3: out_h[n][h*64+d] = sum_m attn[h][n][m] * v[m][h*64+d] ----------------
// BM=32 (n), BN=64 (d), BK=32 (m), 128 threads (16x8), 4x4 micro.
__global__ __launch_bounds__(128) void pv_kernel(const float* __restrict__ attn,
                                                 const float* __restrict__ v_ws,
                                                 float* __restrict__ out_heads) {
    __shared__ float As[32][36];   // [m(k)][n]
    __shared__ float Bs[32][68];   // [m(k)][d]
    const int h  = blockIdx.z;
    const int n0 = blockIdx.y * 32;
    const int t  = threadIdx.x;
    const int tx = t & 15, ty = t >> 4;   // tx: d/4 (16), ty: n/4 (8)
    const float* Ah = attn + (size_t)h * N_TOK * N_TOK;

    float acc[4][4] = {};

    for (int k0 = 0; k0 < N_TOK; k0 += 32) {
        #pragma unroll
        for (int i = 0; i < 2; ++i) {           // A: 32n x 32m = 256 float4
            int fi  = i * 128 + t;
            int row = fi >> 3, k4 = fi & 7;
            float4 a = *(const float4*)(Ah + (size_t)(n0 + row) * N_TOK + k0 + k4 * 4);
            As[k4 * 4 + 0][row] = a.x; As[k4 * 4 + 1][row] = a.y;
            As[k4 * 4 + 2][row] = a.z; As[k4 * 4 + 3][row] = a.w;
        }
        #pragma unroll
        for (int i = 0; i < 4; ++i) {           // B: 32m x 64d = 512 float4
            int fi  = i * 128 + t;
            int row = fi >> 4, d4 = fi & 15;
            float4 b = *(const float4*)(v_ws + (size_t)(k0 + row) * 512 + h * 64 + d4 * 4);
            *(float4*)&Bs[row][d4 * 4] = b;
        }
        __syncthreads();
        #pragma unroll
        for (int k = 0; k < 32; ++k) {
            float4 a4 = *(const float4*)&As[k][ty * 4];
            float4 b4 = *(const float4*)&Bs[k][tx * 4];
            float av[4] = {a4.x, a4.y, a4.z, a4.w};
            float bv[4] = {b4.x, b4.y, b4.z, b4.w};
            #pragma unroll
            for (int i = 0; i < 4; ++i)
                #pragma unroll
                for (int j = 0; j < 4; ++j)
                    acc[i][j] = fmaf(av[i], bv[j], acc[i][j]);
        }
        __syncthreads();
    }

    #pragma unroll
    for (int i = 0; i < 4; ++i) {
        float4 o = {acc[i][0], acc[i][1], acc[i][2], acc[i][3]};
        *(float4*)(out_heads + (size_t)(n0 + ty * 4 + i) * 512 + h * 64 + tx * 4) = o;
    }
}

extern "C" void kernel_launch(void* const* d_in, const int* in_sizes, int n_in,
                              void* d_out, int out_size, void* d_ws, size_t ws_size,
                              hipStream_t stream) {
    const float* x   = (const float*)d_in[0];
    const float* xyz = (const float*)d_in[1];
    const float* Wq  = (const float*)d_in[2];
    const float* bq  = (const float*)d_in[3];
    const float* Wk  = (const float*)d_in[4];
    const float* bk  = (const float*)d_in[5];
    const float* Wv  = (const float*)d_in[6];
    const float* bv  = (const float*)d_in[7];
    const float* Wo  = (const float*)d_in[8];
    const float* bo  = (const float*)d_in[9];
    const float* W1  = (const float*)d_in[10];
    const float* b1  = (const float*)d_in[11];
    const float* W2  = (const float*)d_in[12];
    const float* b2  = (const float*)d_in[13];

    float* out      = (float*)d_out;
    float* attn_out = out + (size_t)N_TOK * DM;           // [8][2048][2048]

    float* ws = (float*)d_ws;
    float* qw = ws;                                        // [2048][512]
    float* kw = ws + 1048576;
    float* vw = ws + 2097152;
    float* U  = ws + 3145728;                              // [2048][32]
    float* oh = ws + 3145728 + 65536;                      // [2048][512]

    u_kernel<<<256, 256, 0, stream>>>(xyz, W1, U);
    gemm_awt<<<dim3(8, 32), 256, 0, stream>>>(x, Wq, bq, qw);
    gemm_awt<<<dim3(8, 32), 256, 0, stream>>>(x, Wk, bk, kw);
    gemm_awt<<<dim3(8, 32), 256, 0, stream>>>(x, Wv, bv, vw);

    const int smem_bytes = (8 * 2048 + 512 + 256 + 8) * 4;   // 68640 B
    hipFuncSetAttribute((const void*)attn_kernel,
                        hipFuncAttributeMaxDynamicSharedMemorySize, smem_bytes);
    attn_kernel<<<dim3(256, 8), 256, smem_bytes, stream>>>(qw, kw, U, b1, W2, b2, attn_out);

    pv_kernel<<<dim3(1, 64, 8), 128, 0, stream>>>(attn_out, vw, oh);
    gemm_awt<<<dim3(8, 32), 256, 0, stream>>>(oh, Wo, bo, out);
}